// Round 9
// baseline (429.491 us; speedup 1.0000x reference)
//
#include <hip/hip_runtime.h>
#include <hip/hip_bf16.h>

typedef __attribute__((ext_vector_type(8))) short short8;
typedef __attribute__((ext_vector_type(16))) float f32x16;

typedef const __attribute__((address_space(1))) unsigned int* gas1_t;
typedef __attribute__((address_space(3))) unsigned int* las3_t;

__device__ __forceinline__ unsigned short f2bf(float x) {
    unsigned int u = __float_as_uint(x);
    u = (u + 0x7fffu + ((u >> 16) & 1u)) >> 16;   // RNE
    return (unsigned short)u;
}

__device__ __forceinline__ int4 pack8(const unsigned short* u) {
    int4 p;
    p.x = (int)((unsigned)u[0] | ((unsigned)u[1] << 16));
    p.y = (int)((unsigned)u[2] | ((unsigned)u[3] << 16));
    p.z = (int)((unsigned)u[4] | ((unsigned)u[5] << 16));
    p.w = (int)((unsigned)u[6] | ((unsigned)u[7] << 16));
    return p;
}

__device__ __forceinline__ void gld_lds16(const void* g, void* l) {
    __builtin_amdgcn_global_load_lds((gas1_t)g, (las3_t)l, 16, 0, 0);
}

// ---------------------------------------------------------------------------
// s[cv][b][c] = 1 + PixelNorm(EqualLinear(latent)); grid 16, block 256
__global__ void style_kernel(const float* __restrict__ latent,
                             const float* __restrict__ elw0, const float* __restrict__ elb0,
                             const float* __restrict__ elw1, const float* __restrict__ elb1,
                             float* __restrict__ s_arr) {
    const int cv = blockIdx.x >> 3;
    const int b  = blockIdx.x & 7;
    const int c  = threadIdx.x;
    const float* elw = cv ? elw1 : elw0;
    const float* elb = cv ? elb1 : elb0;

    __shared__ float lat[512];
    lat[c] = latent[b * 512 + c];
    lat[c + 256] = latent[b * 512 + c + 256];
    __syncthreads();

    float accv = 0.f;
    const float* wrow = elw + (size_t)c * 512;
#pragma unroll 8
    for (int k = 0; k < 512; ++k) accv += lat[k] * wrow[k];
    const float lin = accv * 0.04419417382415922f + elb[c];

    float sq = lin * lin;
#pragma unroll
    for (int off = 32; off >= 1; off >>= 1) sq += __shfl_xor(sq, off);
    __shared__ float wsum[4];
    if ((threadIdx.x & 63) == 0) wsum[threadIdx.x >> 6] = sq;
    __syncthreads();
    const float total = wsum[0] + wsum[1] + wsum[2] + wsum[3];
    const float s = 1.0f + lin * rsqrtf(total * (1.0f / 256.0f) + 1e-8f);
    s_arr[(cv * 8 + b) * 256 + c] = s;
}

// wsq[cv][o][c] = sum_t (w*sc)^2 ; grid 512, block 256
__global__ void wsq_kernel(const float* __restrict__ w0, const float* __restrict__ w1,
                           float* __restrict__ wsq) {
    const int cv = blockIdx.x >> 8;
    const int o  = blockIdx.x & 255;
    const int c  = threadIdx.x;
    const float* w = cv ? w1 : w0;
    const size_t base = ((size_t)o * 256 + c) * 9;
    float ssum = 0.f;
#pragma unroll
    for (int t = 0; t < 9; ++t) { float v = w[base + t]; ssum += v * v; }
    wsq[((size_t)cv * 256 + o) * 256 + c] = ssum * (2.0f / 2304.0f);
}

// d[cv][b][o] = rsqrt(sum_c s^2 * wsq + 1e-5) ; grid 16, block 256
__global__ void demod_kernel(const float* __restrict__ s_arr, const float* __restrict__ wsq,
                             float* __restrict__ d_arr) {
    const int cv = blockIdx.x >> 3;
    const int b  = blockIdx.x & 7;
    const int o  = threadIdx.x;
    __shared__ float ss[256];
    float sv = s_arr[(cv * 8 + b) * 256 + o];
    ss[o] = sv * sv;
    __syncthreads();
    const float* wrow = wsq + ((size_t)cv * 256 + o) * 256;
    float accv = 0.f;
#pragma unroll 8
    for (int c = 0; c < 256; ++c) accv += ss[c] * wrow[c];
    d_arr[(cv * 8 + b) * 256 + o] = rsqrtf(accv + 1e-5f);
}

// wmod[b][cc][t] slab (8192 elems) laid out [k-octet 0..3][o 0..255][8 ch]
// -> lane-contiguous 16B fragments. grid (18432,2), block 256
__global__ void fold_kernel(const float* __restrict__ w0, const float* __restrict__ w1,
                            const float* __restrict__ s_arr, const float* __restrict__ d_arr,
                            unsigned short* __restrict__ wm0, unsigned short* __restrict__ wm1) {
    const int cv = blockIdx.y;
    const int e  = blockIdx.x * 256 + threadIdx.x;       // 0 .. 4718591
    const float* w = cv ? w1 : w0;
    unsigned short* wm = cv ? wm1 : wm0;
    const int slab = e >> 13;            // 0..575  = ((b*8)+cc)*9 + t
    const int idx  = e & 8191;
    const int b  = slab / 72;
    const int s2 = slab - b * 72;
    const int cc = s2 / 9;
    const int t  = s2 - cc * 9;
    const int o  = idx >> 5;
    const int c5 = idx & 31;
    const int c  = cc * 32 + c5;
    const float val = w[((size_t)o * 256 + c) * 9 + t] * 0.029462782549439483f  // sqrt(2/2304)
                    * s_arr[(cv * 8 + b) * 256 + c] * d_arr[(cv * 8 + b) * 256 + o];
    wm[((size_t)slab << 13) + (c5 >> 3) * 2048 + o * 8 + (c5 & 7)] = f2bf(val);
}

// x (fp32 NCHW) -> xq (bf16 NHWC8): [b][g=32][h][w][8ch]; grid 32768, block 256
__global__ void convert_kernel(const float* __restrict__ x, unsigned short* __restrict__ xq) {
    const int blk = blockIdx.x;
    const int hh  = blk & 127;
    const int bg_ = blk >> 7;
    const int g   = bg_ & 31;
    const int b   = bg_ >> 5;
    __shared__ float sx[8][128];
    const int tid = threadIdx.x;
#pragma unroll
    for (int i = 0; i < 4; ++i) {
        const int idx = tid + i * 256;
        const int c8 = idx >> 7, p = idx & 127;
        sx[c8][p] = x[(((size_t)b * 256 + g * 8 + c8) * 128 + hh) * 128 + p];
    }
    __syncthreads();
    if (tid < 128) {
        const int p = tid;
        unsigned short u[8];
#pragma unroll
        for (int j = 0; j < 8; ++j) u[j] = f2bf(sx[j][p]);
        *(int4*)(xq + ((((size_t)b * 32 + g) * 128 + hh) * 128 + p) * 8) = pack8(u);
    }
}

// ---------------------------------------------------------------------------
// Modulated conv, implicit GEMM: M=256 (o), N=64 (half row), K=2304.
// 4 waves (256 thr), wave tile 64o x 64px (acc=64) -> ~150 regs/wave ->
// 3 blocks/CU via __launch_bounds__(256,3); the 3 waves/SIMD come from 3
// INDEPENDENT blocks (no barrier correlation) -> staging hides under MFMA.
// A: per-wave global->VGPR, double-banked one tap ahead (compiler waits only).
// B: LDS, 3 rows x 128px, double-buffered per cc, staged a full cc ahead.
// ONE barrier per cc; all manual waits are vmcnt(0) (unconditionally safe).
// Fused: +bias, leaky*sqrt2, PixelNorm; !FINAL_OUT -> NHWC8 bf16, else fp32 NCHW.
template<bool FINAL_OUT>
__global__ __launch_bounds__(256, 3) void conv_kernel(
    const unsigned short* __restrict__ in_q, const unsigned short* __restrict__ wmod,
    const float* __restrict__ bias, const unsigned short* __restrict__ zpg,
    void* __restrict__ out_v) {

    // [0,49152) B: 2 buffers x (3 rows x 4 koct x 128px x 16B)
    // [49152,49216) zero slot  [49216,50240) bias  [50240,51264) red
    __shared__ __align__(16) char lds[51264];

    const int tid  = threadIdx.x;
    const int b    = blockIdx.x & 7;              // XCD-affine (image b -> XCD b)
    const int h    = (blockIdx.x >> 3) & 127;     // output row
    const int half = blockIdx.x >> 10;            // px half: 0 -> [0,64), 1 -> [64,128)
    const int lane = tid & 63;
    const int wr   = tid >> 6;                    // 0..3 = o-quarter (64 o's)
    const int wm   = wr;
    const int l31  = lane & 31;
    const int khg  = lane >> 5;                   // k-octet half

    float* sbias = (float*)(lds + 49216);
    sbias[tid] = bias[tid];
    if (tid < 4) *(int4*)(lds + 49152 + tid * 16) = (int4){0, 0, 0, 0};

    const unsigned short* wmb = wmod + (size_t)b * 589824;
    const unsigned short* xqb = in_q + (size_t)b * 4194304;   // [32][128][128][8]
    // per-lane A base: slab layout [koct][o][16B]; koct = khg + 2*kh
    const char* aLane = (const char*)wmb + khg * 4096 + (wm * 64 + l31) * 16;

    auto issueB = [&](int cc, int buf) {
        const int px    = tid & 127;              // (wr&1)*64 + lane -> lane-contiguous
        const int kbase = tid >> 7;               // wr>>1 (wave-uniform)
#pragma unroll
        for (int r = 0; r < 3; ++r) {
            const int hin = h + r - 1;
            const bool ok = (unsigned)hin < 128u;
#pragma unroll
            for (int i = 0; i < 2; ++i) {
                const int koct = i * 2 + kbase;
                const unsigned short* src = ok
                    ? xqb + (((size_t)(cc * 4 + koct) * 128 + hin) * 128 + px) * 8
                    : zpg;
                gld_lds16(src, lds + buf * 24576 + r * 8192 + koct * 2048
                               + (wr & 1) * 1024);             // wave-uniform base
            }
        }
    };

    short8 afA[2][2], afB[2][2];
    auto loadA = [&](int s, short8 (&af)[2][2]) {
        const char* p = aLane + (size_t)s * 16384;
        af[0][0] = *(const short8*)(p);            // mb0, kh0
        af[1][0] = *(const short8*)(p + 512);      // mb1 (+32 o)
        af[0][1] = *(const short8*)(p + 8192);     // kh1 (+2 koct)
        af[1][1] = *(const short8*)(p + 8704);
    };

    f32x16 acc[2][2];
#pragma unroll
    for (int mb = 0; mb < 2; ++mb)
#pragma unroll
        for (int nb = 0; nb < 2; ++nb)
#pragma unroll
            for (int r = 0; r < 16; ++r) acc[mb][nb][r] = 0.f;

    // one tap of the K loop; cur/nxt are static register banks (rule #20 safe)
    auto tap = [&](int s, short8 (&cur)[2][2], short8 (&nxt)[2][2]) {
        const int cc = s / 9;
        const int t  = s - cc * 9;
        if (t == 0) {
            if (s) {   // cc boundary: full drain (safe) + barrier
                asm volatile("s_waitcnt vmcnt(0) lgkmcnt(0)" ::: "memory");
                __builtin_amdgcn_sched_barrier(0);
                __builtin_amdgcn_s_barrier();
            }
            if (cc < 7) issueB(cc + 1, (cc + 1) & 1);
        }
        if (s < 71) loadA(s + 1, nxt);   // prefetch next tap's A into other bank

        const int dy = t / 3, dx = t - dy * 3;
        const int ob = (cc & 1) * 24576 + dy * 8192 + khg * 2048
                     + (half * 64 + dx - 1) * 16;
        short8 bf[2][2];
#pragma unroll
        for (int nb = 0; nb < 2; ++nb)
#pragma unroll
            for (int kh = 0; kh < 2; ++kh) {
                int off = ob + kh * 4096 + (nb * 32 + l31) * 16;
                if (nb == 0 && dx == 0) off = (l31 == 0  && half == 0) ? 49152 : off;
                if (nb == 1 && dx == 2) off = (l31 == 31 && half == 1) ? 49152 : off;
                bf[nb][kh] = *(const short8*)(lds + off);
            }
        __builtin_amdgcn_s_setprio(1);
#pragma unroll
        for (int kh = 0; kh < 2; ++kh)
#pragma unroll
            for (int mb = 0; mb < 2; ++mb)
#pragma unroll
                for (int nb = 0; nb < 2; ++nb)
                    acc[mb][nb] = __builtin_amdgcn_mfma_f32_32x32x16_bf16(
                        cur[mb][kh], bf[nb][kh], acc[mb][nb], 0, 0, 0);
        __builtin_amdgcn_s_setprio(0);
    };

    // prologue: B(cc0) -> buf0, A slab0 -> bank A
    issueB(0, 0);
    loadA(0, afA);
    __syncthreads();   // compiler drains vmcnt before barrier

#pragma unroll 1
    for (int ss = 0; ss < 72; ss += 2) {
        tap(ss,     afA, afB);
        tap(ss + 1, afB, afA);
    }

    // ---------------- epilogue: bias + leaky*sqrt2 + PixelNorm ----------------
    float psum[2] = {0.f, 0.f};
    const float actGain = 1.4142135623730951f;
#pragma unroll
    for (int mb = 0; mb < 2; ++mb)
#pragma unroll
        for (int rg = 0; rg < 16; ++rg) {
            const int row = (rg & 3) + 8 * (rg >> 2) + 4 * khg;
            const float bo = sbias[wm * 64 + mb * 32 + row];
#pragma unroll
            for (int nb = 0; nb < 2; ++nb) {
                float v = acc[mb][nb][rg] + bo;
                v = (v > 0.f ? v : 0.2f * v) * actGain;
                acc[mb][nb][rg] = v;
                psum[nb] += v * v;
            }
        }
    psum[0] += __shfl_xor(psum[0], 32);
    psum[1] += __shfl_xor(psum[1], 32);
    float* red = (float*)(lds + 50240);       // [4 waves][64 px]
    if (lane < 32) {
        red[wr * 64 + l31]      = psum[0];
        red[wr * 64 + 32 + l31] = psum[1];
    }
    __syncthreads();
    float rs[2];
#pragma unroll
    for (int nb = 0; nb < 2; ++nb) {
        const int p = nb * 32 + l31;
        const float ssum = red[p] + red[64 + p] + red[128 + p] + red[192 + p];
        rs[nb] = rsqrtf(ssum * (1.0f / 256.0f) + 1e-8f);
    }

    if (FINAL_OUT) {
        float* outF = (float*)out_v;
#pragma unroll
        for (int mb = 0; mb < 2; ++mb)
#pragma unroll
            for (int rg = 0; rg < 16; ++rg) {
                const int row = (rg & 3) + 8 * (rg >> 2) + 4 * khg;
                const int o = wm * 64 + mb * 32 + row;
                const size_t rb = (((size_t)b * 256 + o) * 128 + h) * 128 + half * 64;
#pragma unroll
                for (int nb = 0; nb < 2; ++nb)
                    outF[rb + nb * 32 + l31] = acc[mb][nb][rg] * rs[nb];
            }
    } else {
        // per-wave transpose 64o x 64px -> NHWC8 bf16, fully unrolled (rule #20)
        unsigned short* outB = (unsigned short*)out_v;
        char* wreg = lds + wr * 4096;         // [64 px][32 o] bf16, chunk-swizzled
#pragma unroll
        for (int mb = 0; mb < 2; ++mb) {
#pragma unroll
            for (int rg = 0; rg < 16; rg += 2) {
                const int row = (rg & 3) + 8 * (rg >> 2) + 4 * khg;   // even, 0..31
#pragma unroll
                for (int nb = 0; nb < 2; ++nb) {
                    const int pxl = nb * 32 + l31;
                    const unsigned lo = f2bf(acc[mb][nb][rg]     * rs[nb]);
                    const unsigned hi = f2bf(acc[mb][nb][rg + 1] * rs[nb]);
                    *(unsigned int*)(wreg + pxl * 64 + (((row >> 3) ^ (pxl & 3)) << 4)
                                     + (row & 7) * 2) = lo | (hi << 16);
                }
            }
            asm volatile("s_waitcnt lgkmcnt(0)" ::: "memory");
#pragma unroll
            for (int oc = 0; oc < 4; ++oc) {
                const int pxl = lane;
                const int4 v = *(const int4*)(wreg + pxl * 64 + ((oc ^ (pxl & 3)) << 4));
                const int g = wm * 8 + mb * 4 + oc;
                *(int4*)(outB + ((((size_t)b * 32 + g) * 128 + h) * 128
                                 + half * 64 + pxl) * 8) = v;
            }
            asm volatile("s_waitcnt lgkmcnt(0)" ::: "memory");
        }
    }
}

// ---------------------------------------------------------------------------
extern "C" void kernel_launch(void* const* d_in, const int* in_sizes, int n_in,
                              void* d_out, int out_size, void* d_ws, size_t ws_size,
                              hipStream_t stream) {
    (void)in_sizes; (void)n_in; (void)out_size; (void)ws_size;
    const float* x      = (const float*)d_in[0];
    const float* latent = (const float*)d_in[1];
    const float* w0     = (const float*)d_in[2];
    const float* b0     = (const float*)d_in[3];
    const float* el0w   = (const float*)d_in[4];
    const float* el0b   = (const float*)d_in[5];
    const float* w1     = (const float*)d_in[6];
    const float* b1     = (const float*)d_in[7];
    const float* el1w   = (const float*)d_in[8];
    const float* el1b   = (const float*)d_in[9];

    char* ws = (char*)d_ws;
    float* s_arr = (float*)ws;                                   // 16 KB
    float* d_arr = (float*)(ws + 16384);                         // 16 KB
    float* wsq   = (float*)(ws + 32768);                         // 512 KB (reused as zero page)
    unsigned short* zpg = (unsigned short*)(ws + 32768);         // 256 B zeros (after demod)
    unsigned short* wm0 = (unsigned short*)(ws + 557056);        // 9.4 MB
    unsigned short* wm1 = (unsigned short*)(ws + 9994240);       // 9.4 MB
    unsigned short* xq  = (unsigned short*)(ws + 19431424);      // 67 MB
    unsigned short* tmp = (unsigned short*)(ws + 86540288);      // 67 MB

    style_kernel<<<16, 256, 0, stream>>>(latent, el0w, el0b, el1w, el1b, s_arr);
    wsq_kernel<<<512, 256, 0, stream>>>(w0, w1, wsq);
    demod_kernel<<<16, 256, 0, stream>>>(s_arr, wsq, d_arr);
    hipMemsetAsync(zpg, 0, 256, stream);   // wsq no longer needed; reuse as zero page
    fold_kernel<<<dim3(18432, 2), 256, 0, stream>>>(w0, w1, s_arr, d_arr, wm0, wm1);
    convert_kernel<<<32768, 256, 0, stream>>>(x, xq);

    conv_kernel<false><<<2048, 256, 0, stream>>>(xq, wm0, b0, zpg, tmp);
    conv_kernel<true><<<2048, 256, 0, stream>>>(tmp, wm1, b1, zpg, d_out);
}

// Round 10
// 369.397 us; speedup vs baseline: 1.1627x; 1.1627x over previous
//
#include <hip/hip_runtime.h>
#include <hip/hip_bf16.h>

typedef __attribute__((ext_vector_type(8))) short short8;
typedef __attribute__((ext_vector_type(16))) float f32x16;

typedef const __attribute__((address_space(1))) unsigned int* gas1_t;
typedef __attribute__((address_space(3))) unsigned int* las3_t;

__device__ __forceinline__ unsigned short f2bf(float x) {
    unsigned int u = __float_as_uint(x);
    u = (u + 0x7fffu + ((u >> 16) & 1u)) >> 16;   // RNE
    return (unsigned short)u;
}

__device__ __forceinline__ int4 pack8(const unsigned short* u) {
    int4 p;
    p.x = (int)((unsigned)u[0] | ((unsigned)u[1] << 16));
    p.y = (int)((unsigned)u[2] | ((unsigned)u[3] << 16));
    p.z = (int)((unsigned)u[4] | ((unsigned)u[5] << 16));
    p.w = (int)((unsigned)u[6] | ((unsigned)u[7] << 16));
    return p;
}

__device__ __forceinline__ void gld_lds16(const void* g, void* l) {
    __builtin_amdgcn_global_load_lds((gas1_t)g, (las3_t)l, 16, 0, 0);
}

// ---------------------------------------------------------------------------
// s[cv][b][c] = 1 + PixelNorm(EqualLinear(latent)); grid 16, block 256
__global__ void style_kernel(const float* __restrict__ latent,
                             const float* __restrict__ elw0, const float* __restrict__ elb0,
                             const float* __restrict__ elw1, const float* __restrict__ elb1,
                             float* __restrict__ s_arr) {
    const int cv = blockIdx.x >> 3;
    const int b  = blockIdx.x & 7;
    const int c  = threadIdx.x;
    const float* elw = cv ? elw1 : elw0;
    const float* elb = cv ? elb1 : elb0;

    __shared__ float lat[512];
    lat[c] = latent[b * 512 + c];
    lat[c + 256] = latent[b * 512 + c + 256];
    __syncthreads();

    float accv = 0.f;
    const float* wrow = elw + (size_t)c * 512;
#pragma unroll 8
    for (int k = 0; k < 512; ++k) accv += lat[k] * wrow[k];
    const float lin = accv * 0.04419417382415922f + elb[c];

    float sq = lin * lin;
#pragma unroll
    for (int off = 32; off >= 1; off >>= 1) sq += __shfl_xor(sq, off);
    __shared__ float wsum[4];
    if ((threadIdx.x & 63) == 0) wsum[threadIdx.x >> 6] = sq;
    __syncthreads();
    const float total = wsum[0] + wsum[1] + wsum[2] + wsum[3];
    const float s = 1.0f + lin * rsqrtf(total * (1.0f / 256.0f) + 1e-8f);
    s_arr[(cv * 8 + b) * 256 + c] = s;
}

// wsq[cv][o][c] = sum_t (w*sc)^2 ; grid 512, block 256
__global__ void wsq_kernel(const float* __restrict__ w0, const float* __restrict__ w1,
                           float* __restrict__ wsq) {
    const int cv = blockIdx.x >> 8;
    const int o  = blockIdx.x & 255;
    const int c  = threadIdx.x;
    const float* w = cv ? w1 : w0;
    const size_t base = ((size_t)o * 256 + c) * 9;
    float ssum = 0.f;
#pragma unroll
    for (int t = 0; t < 9; ++t) { float v = w[base + t]; ssum += v * v; }
    wsq[((size_t)cv * 256 + o) * 256 + c] = ssum * (2.0f / 2304.0f);
}

// d[cv][b][o] = rsqrt(sum_c s^2 * wsq + 1e-5) ; grid 16, block 256
__global__ void demod_kernel(const float* __restrict__ s_arr, const float* __restrict__ wsq,
                             float* __restrict__ d_arr) {
    const int cv = blockIdx.x >> 3;
    const int b  = blockIdx.x & 7;
    const int o  = threadIdx.x;
    __shared__ float ss[256];
    float sv = s_arr[(cv * 8 + b) * 256 + o];
    ss[o] = sv * sv;
    __syncthreads();
    const float* wrow = wsq + ((size_t)cv * 256 + o) * 256;
    float accv = 0.f;
#pragma unroll 8
    for (int c = 0; c < 256; ++c) accv += ss[c] * wrow[c];
    d_arr[(cv * 8 + b) * 256 + o] = rsqrtf(accv + 1e-5f);
}

// wmod[b][cc][t] slab (8192 elems) laid out [k-octet 0..3][o 0..255][8 ch]
// -> lane-contiguous 16B fragments. grid (18432,2), block 256
__global__ void fold_kernel(const float* __restrict__ w0, const float* __restrict__ w1,
                            const float* __restrict__ s_arr, const float* __restrict__ d_arr,
                            unsigned short* __restrict__ wm0, unsigned short* __restrict__ wm1) {
    const int cv = blockIdx.y;
    const int e  = blockIdx.x * 256 + threadIdx.x;       // 0 .. 4718591
    const float* w = cv ? w1 : w0;
    unsigned short* wm = cv ? wm1 : wm0;
    const int slab = e >> 13;            // 0..575  = ((b*8)+cc)*9 + t
    const int idx  = e & 8191;
    const int b  = slab / 72;
    const int s2 = slab - b * 72;
    const int cc = s2 / 9;
    const int t  = s2 - cc * 9;
    const int o  = idx >> 5;
    const int c5 = idx & 31;
    const int c  = cc * 32 + c5;
    const float val = w[((size_t)o * 256 + c) * 9 + t] * 0.029462782549439483f  // sqrt(2/2304)
                    * s_arr[(cv * 8 + b) * 256 + c] * d_arr[(cv * 8 + b) * 256 + o];
    wm[((size_t)slab << 13) + (c5 >> 3) * 2048 + o * 8 + (c5 & 7)] = f2bf(val);
}

// x (fp32 NCHW) -> xq (bf16 NHWC8): [b][g=32][h][w][8ch]; grid 32768, block 256
__global__ void convert_kernel(const float* __restrict__ x, unsigned short* __restrict__ xq) {
    const int blk = blockIdx.x;
    const int hh  = blk & 127;
    const int bg_ = blk >> 7;
    const int g   = bg_ & 31;
    const int b   = bg_ >> 5;
    __shared__ float sx[8][128];
    const int tid = threadIdx.x;
#pragma unroll
    for (int i = 0; i < 4; ++i) {
        const int idx = tid + i * 256;
        const int c8 = idx >> 7, p = idx & 127;
        sx[c8][p] = x[(((size_t)b * 256 + g * 8 + c8) * 128 + hh) * 128 + p];
    }
    __syncthreads();
    if (tid < 128) {
        const int p = tid;
        unsigned short u[8];
#pragma unroll
        for (int j = 0; j < 8; ++j) u[j] = f2bf(sx[j][p]);
        *(int4*)(xq + ((((size_t)b * 32 + g) * 128 + hh) * 128 + p) * 8) = pack8(u);
    }
}

// ---------------------------------------------------------------------------
// Modulated conv, implicit GEMM: M=256 (o), N=256 (2 rows x 128 px), K=2304.
// 8 waves, wave tile 64o x 128px (R5 geometry). REGION SCHEDULE: one barrier
// region = one dy row = 3 taps = 48 MFMAs/wave; A staged per region (3 slabs,
// 48KB) double-buffered via global_load_lds, prefetched a full region (~3000cy)
// ahead so the region-end vmcnt(0) drain is free. B single-buffered (4 rows),
// staged per cc behind its own barrier. Barriers: 81 (R5) -> 32.
// All manual waits vmcnt(0) (unconditionally safe, R7 lesson).
// Fused: +bias, leaky*sqrt2, PixelNorm; !FINAL_OUT -> NHWC8 bf16, else fp32 NCHW.
template<bool FINAL_OUT>
__global__ __launch_bounds__(512, 2) void conv_kernel(
    const unsigned short* __restrict__ in_q, const unsigned short* __restrict__ wmod,
    const float* __restrict__ bias, const unsigned short* __restrict__ zpg,
    void* __restrict__ out_v) {

    // [0,98304)       A: 2 region-buffers x 3 slabs x 16KB
    // [98304,131072)  B: 4 rows x 4 koct x 128 px x 16B (single buffer)
    // [131072,131136) zero slot   [131136,132160) bias   [132160,136256) red
    __shared__ __align__(16) char lds[136256];

    const int tid  = threadIdx.x;
    const int b    = blockIdx.x & 7;          // XCD-affine (image b -> XCD b)
    const int rp   = blockIdx.x >> 3;         // 0..63 row pair
    const int h0   = rp * 2;
    const int lane = tid & 63;
    const int wr   = tid >> 6;                // 0..7
    const int wm   = wr & 3;                  // o-quarter (64 o's)
    const int wn   = wr >> 2;                 // row within pair
    const int l31  = lane & 31;
    const int khg  = lane >> 5;               // k-octet half

    float* sbias = (float*)(lds + 131136);
    if (tid < 256) sbias[tid] = bias[tid];
    if (tid < 4)   *(int4*)(lds + 131072 + tid * 16) = (int4){0, 0, 0, 0};

    // A frag byte offsets within a slab: [koct][o][16B]
    int aoff[2][2];
#pragma unroll
    for (int mb = 0; mb < 2; ++mb)
#pragma unroll
        for (int kh = 0; kh < 2; ++kh)
            aoff[mb][kh] = ((khg + 2 * kh) * 256 + wm * 64 + mb * 32 + l31) * 16;

    const unsigned short* wmb = wmod + (size_t)b * 589824;
    const unsigned short* xqb = in_q + (size_t)b * 4194304;   // [32][128][128][8]

    // stage 3 slabs (one region, 48KB) into region buffer nbuf
    auto issueA3 = [&](const char* src, int nbuf) {
        char* db = lds + nbuf * 49152 + wr * 2048;           // wave-uniform base
        const char* s = src + wr * 2048 + lane * 16;
#pragma unroll
        for (int j = 0; j < 3; ++j) {
            gld_lds16(s + j * 16384,        db + j * 16384);
            gld_lds16(s + j * 16384 + 1024, db + j * 16384 + 1024);
        }
    };

    auto issueB = [&](int cc) {
        const int koct = tid >> 7;            // wave-uniform (wr>>1)
        const int px   = tid & 127;
#pragma unroll
        for (int r = 0; r < 4; ++r) {
            const int hin = h0 - 1 + r;
            const unsigned short* src = ((unsigned)hin < 128u)
                ? xqb + (((size_t)(cc * 4 + koct) * 128 + hin) * 128 + px) * 8
                : zpg;
            gld_lds16(src, lds + 98304 + r * 8192 + koct * 2048 + (wr & 1) * 1024);
        }
    };

    f32x16 acc[2][4];
#pragma unroll
    for (int mb = 0; mb < 2; ++mb)
#pragma unroll
        for (int nb = 0; nb < 4; ++nb)
#pragma unroll
            for (int r = 0; r < 16; ++r) acc[mb][nb][r] = 0.f;

    // prologue: region 0 A + B(cc0); full drain via __syncthreads
    issueA3((const char*)wmb, 0);
    issueB(0);
    __syncthreads();

    const char* gA = (const char*)wmb + 49152;   // region 1 onward
#pragma unroll 1
    for (int cc = 0; cc < 8; ++cc) {
        if (cc > 0) {
            issueB(cc);                           // B buffer free (barrier passed)
            asm volatile("s_waitcnt vmcnt(0)" ::: "memory");
            __builtin_amdgcn_sched_barrier(0);
            __builtin_amdgcn_s_barrier();
        }
#pragma unroll
        for (int r = 0; r < 3; ++r) {             // region = dy row = 3 taps
            const int g = cc * 3 + r;
            if (g < 23) { issueA3(gA, (g + 1) & 1); gA += 49152; }
            const char* Ac = lds + (g & 1) * 49152;
#pragma unroll
            for (int i = 0; i < 3; ++i) {         // tap: dx = i
                short8 af[2][2], bf[4][2];
#pragma unroll
                for (int mb = 0; mb < 2; ++mb)
#pragma unroll
                    for (int kh = 0; kh < 2; ++kh)
                        af[mb][kh] = *(const short8*)(Ac + i * 16384 + aoff[mb][kh]);
#pragma unroll
                for (int nb = 0; nb < 4; ++nb)
#pragma unroll
                    for (int kh = 0; kh < 2; ++kh) {
                        int off = 98304 + (wn + r) * 8192 + (khg + 2 * kh) * 2048
                                + (nb * 32 + l31 + i - 1) * 16;
                        if (i == 0 && nb == 0) off = (l31 == 0)  ? 131072 : off;
                        if (i == 2 && nb == 3) off = (l31 == 31) ? 131072 : off;
                        bf[nb][kh] = *(const short8*)(lds + off);
                    }
                __builtin_amdgcn_s_setprio(1);
#pragma unroll
                for (int kh = 0; kh < 2; ++kh)
#pragma unroll
                    for (int mb = 0; mb < 2; ++mb)
#pragma unroll
                        for (int nb = 0; nb < 4; ++nb)
                            acc[mb][nb] = __builtin_amdgcn_mfma_f32_32x32x16_bf16(
                                af[mb][kh], bf[nb][kh], acc[mb][nb], 0, 0, 0);
                __builtin_amdgcn_s_setprio(0);
            }
            // region end: A(g+1) has been in flight ~3 taps -> drain is free
            asm volatile("s_waitcnt vmcnt(0) lgkmcnt(0)" ::: "memory");
            __builtin_amdgcn_sched_barrier(0);
            __builtin_amdgcn_s_barrier();
        }
    }

    // ---------------- epilogue: bias + leaky*sqrt2 + PixelNorm ----------------
    float psum[4] = {0.f, 0.f, 0.f, 0.f};
    const float actGain = 1.4142135623730951f;
#pragma unroll
    for (int mb = 0; mb < 2; ++mb)
#pragma unroll
        for (int rg = 0; rg < 16; ++rg) {
            const int row = (rg & 3) + 8 * (rg >> 2) + 4 * khg;
            const float bo = sbias[wm * 64 + mb * 32 + row];
#pragma unroll
            for (int nb = 0; nb < 4; ++nb) {
                float v = acc[mb][nb][rg] + bo;
                v = (v > 0.f ? v : 0.2f * v) * actGain;
                acc[mb][nb][rg] = v;
                psum[nb] += v * v;
            }
        }
#pragma unroll
    for (int nb = 0; nb < 4; ++nb) psum[nb] += __shfl_xor(psum[nb], 32);
    float* red = (float*)(lds + 132160);      // [wn][wm][128 px]
    if (lane < 32) {
#pragma unroll
        for (int nb = 0; nb < 4; ++nb)
            red[(wn * 4 + wm) * 128 + nb * 32 + l31] = psum[nb];
    }
    __syncthreads();
    float rs[4];
#pragma unroll
    for (int nb = 0; nb < 4; ++nb) {
        const int p = nb * 32 + l31;
        const float ssum = red[(wn * 4 + 0) * 128 + p] + red[(wn * 4 + 1) * 128 + p]
                         + red[(wn * 4 + 2) * 128 + p] + red[(wn * 4 + 3) * 128 + p];
        rs[nb] = rsqrtf(ssum * (1.0f / 256.0f) + 1e-8f);
    }

    const int h = h0 + wn;
    if (FINAL_OUT) {
        float* outF = (float*)out_v;
#pragma unroll
        for (int mb = 0; mb < 2; ++mb)
#pragma unroll
            for (int rg = 0; rg < 16; ++rg) {
                const int row = (rg & 3) + 8 * (rg >> 2) + 4 * khg;
                const int o = wm * 64 + mb * 32 + row;
                const size_t rb = (((size_t)b * 256 + o) * 128 + h) * 128;
#pragma unroll
                for (int nb = 0; nb < 4; ++nb)
                    outF[rb + nb * 32 + l31] = acc[mb][nb][rg] * rs[nb];
            }
    } else {
        // per-wave transpose 32o x 128px -> NHWC8 bf16, fully unrolled (rule #20)
        unsigned short* outB = (unsigned short*)out_v;
        char* wreg = lds + wr * 8192;         // [128 px][32 o] bf16, chunk-swizzled
#pragma unroll
        for (int mb = 0; mb < 2; ++mb) {
#pragma unroll
            for (int rg = 0; rg < 16; rg += 2) {
                const int row = (rg & 3) + 8 * (rg >> 2) + 4 * khg;   // even, 0..31
#pragma unroll
                for (int nb = 0; nb < 4; ++nb) {
                    const int pxl = nb * 32 + l31;
                    const unsigned lo = f2bf(acc[mb][nb][rg]     * rs[nb]);
                    const unsigned hi = f2bf(acc[mb][nb][rg + 1] * rs[nb]);
                    *(unsigned int*)(wreg + pxl * 64 + (((row >> 3) ^ (pxl & 3)) << 4)
                                     + (row & 7) * 2) = lo | (hi << 16);
                }
            }
            asm volatile("s_waitcnt lgkmcnt(0)" ::: "memory");
#pragma unroll
            for (int oc = 0; oc < 4; ++oc)
#pragma unroll
                for (int ph = 0; ph < 2; ++ph) {
                    const int pxl = ph * 64 + lane;
                    const int4 v = *(const int4*)(wreg + pxl * 64 + ((oc ^ (pxl & 3)) << 4));
                    const int g = wm * 8 + mb * 4 + oc;
                    *(int4*)(outB + ((((size_t)b * 32 + g) * 128 + h) * 128 + pxl) * 8) = v;
                }
            asm volatile("s_waitcnt lgkmcnt(0)" ::: "memory");
        }
    }
}

// ---------------------------------------------------------------------------
extern "C" void kernel_launch(void* const* d_in, const int* in_sizes, int n_in,
                              void* d_out, int out_size, void* d_ws, size_t ws_size,
                              hipStream_t stream) {
    (void)in_sizes; (void)n_in; (void)out_size; (void)ws_size;
    const float* x      = (const float*)d_in[0];
    const float* latent = (const float*)d_in[1];
    const float* w0     = (const float*)d_in[2];
    const float* b0     = (const float*)d_in[3];
    const float* el0w   = (const float*)d_in[4];
    const float* el0b   = (const float*)d_in[5];
    const float* w1     = (const float*)d_in[6];
    const float* b1     = (const float*)d_in[7];
    const float* el1w   = (const float*)d_in[8];
    const float* el1b   = (const float*)d_in[9];

    char* ws = (char*)d_ws;
    float* s_arr = (float*)ws;                                   // 16 KB
    float* d_arr = (float*)(ws + 16384);                         // 16 KB
    float* wsq   = (float*)(ws + 32768);                         // 512 KB (reused as zero page)
    unsigned short* zpg = (unsigned short*)(ws + 32768);         // 256 B zeros (after demod)
    unsigned short* wm0 = (unsigned short*)(ws + 557056);        // 9.4 MB
    unsigned short* wm1 = (unsigned short*)(ws + 9994240);       // 9.4 MB
    unsigned short* xq  = (unsigned short*)(ws + 19431424);      // 67 MB
    unsigned short* tmp = (unsigned short*)(ws + 86540288);      // 67 MB

    style_kernel<<<16, 256, 0, stream>>>(latent, el0w, el0b, el1w, el1b, s_arr);
    wsq_kernel<<<512, 256, 0, stream>>>(w0, w1, wsq);
    demod_kernel<<<16, 256, 0, stream>>>(s_arr, wsq, d_arr);
    hipMemsetAsync(zpg, 0, 256, stream);   // wsq no longer needed; reuse as zero page
    fold_kernel<<<dim3(18432, 2), 256, 0, stream>>>(w0, w1, s_arr, d_arr, wm0, wm1);
    convert_kernel<<<32768, 256, 0, stream>>>(x, xq);

    conv_kernel<false><<<512, 512, 0, stream>>>(xq, wm0, b0, zpg, tmp);
    conv_kernel<true><<<512, 512, 0, stream>>>(tmp, wm1, b1, zpg, d_out);
}

// Round 12
// 363.788 us; speedup vs baseline: 1.1806x; 1.0154x over previous
//
#include <hip/hip_runtime.h>
#include <hip/hip_bf16.h>

typedef __attribute__((ext_vector_type(8))) short short8;
typedef __attribute__((ext_vector_type(16))) float f32x16;

typedef const __attribute__((address_space(1))) unsigned int* gas1_t;
typedef __attribute__((address_space(3))) unsigned int* las3_t;

__device__ __forceinline__ unsigned short f2bf(float x) {
    unsigned int u = __float_as_uint(x);
    u = (u + 0x7fffu + ((u >> 16) & 1u)) >> 16;   // RNE
    return (unsigned short)u;
}

__device__ __forceinline__ int4 pack8(const unsigned short* u) {
    int4 p;
    p.x = (int)((unsigned)u[0] | ((unsigned)u[1] << 16));
    p.y = (int)((unsigned)u[2] | ((unsigned)u[3] << 16));
    p.z = (int)((unsigned)u[4] | ((unsigned)u[5] << 16));
    p.w = (int)((unsigned)u[6] | ((unsigned)u[7] << 16));
    return p;
}

__device__ __forceinline__ void gld_lds16(const void* g, void* l) {
    __builtin_amdgcn_global_load_lds((gas1_t)g, (las3_t)l, 16, 0, 0);
}

// ---------------------------------------------------------------------------
// s[cv][b][c] = 1 + PixelNorm(EqualLinear(latent)); grid 16, block 256
__global__ void style_kernel(const float* __restrict__ latent,
                             const float* __restrict__ elw0, const float* __restrict__ elb0,
                             const float* __restrict__ elw1, const float* __restrict__ elb1,
                             float* __restrict__ s_arr) {
    const int cv = blockIdx.x >> 3;
    const int b  = blockIdx.x & 7;
    const int c  = threadIdx.x;
    const float* elw = cv ? elw1 : elw0;
    const float* elb = cv ? elb1 : elb0;

    __shared__ float lat[512];
    lat[c] = latent[b * 512 + c];
    lat[c + 256] = latent[b * 512 + c + 256];
    __syncthreads();

    float accv = 0.f;
    const float* wrow = elw + (size_t)c * 512;
#pragma unroll 8
    for (int k = 0; k < 512; ++k) accv += lat[k] * wrow[k];
    const float lin = accv * 0.04419417382415922f + elb[c];

    float sq = lin * lin;
#pragma unroll
    for (int off = 32; off >= 1; off >>= 1) sq += __shfl_xor(sq, off);
    __shared__ float wsum[4];
    if ((threadIdx.x & 63) == 0) wsum[threadIdx.x >> 6] = sq;
    __syncthreads();
    const float total = wsum[0] + wsum[1] + wsum[2] + wsum[3];
    const float s = 1.0f + lin * rsqrtf(total * (1.0f / 256.0f) + 1e-8f);
    s_arr[(cv * 8 + b) * 256 + c] = s;
}

// wsq[cv][o][c] = sum_t (w*sc)^2 ; grid 512, block 256
__global__ void wsq_kernel(const float* __restrict__ w0, const float* __restrict__ w1,
                           float* __restrict__ wsq) {
    const int cv = blockIdx.x >> 8;
    const int o  = blockIdx.x & 255;
    const int c  = threadIdx.x;
    const float* w = cv ? w1 : w0;
    const size_t base = ((size_t)o * 256 + c) * 9;
    float ssum = 0.f;
#pragma unroll
    for (int t = 0; t < 9; ++t) { float v = w[base + t]; ssum += v * v; }
    wsq[((size_t)cv * 256 + o) * 256 + c] = ssum * (2.0f / 2304.0f);
}

// d[cv][b][o] = rsqrt(sum_c s^2 * wsq + 1e-5) ; grid 16, block 256
__global__ void demod_kernel(const float* __restrict__ s_arr, const float* __restrict__ wsq,
                             float* __restrict__ d_arr) {
    const int cv = blockIdx.x >> 3;
    const int b  = blockIdx.x & 7;
    const int o  = threadIdx.x;
    __shared__ float ss[256];
    float sv = s_arr[(cv * 8 + b) * 256 + o];
    ss[o] = sv * sv;
    __syncthreads();
    const float* wrow = wsq + ((size_t)cv * 256 + o) * 256;
    float accv = 0.f;
#pragma unroll 8
    for (int c = 0; c < 256; ++c) accv += ss[c] * wrow[c];
    d_arr[(cv * 8 + b) * 256 + o] = rsqrtf(accv + 1e-5f);
}

// wmod[b][cc][t] slab (8192 elems) laid out [k-octet 0..3][o 0..255][8 ch]
// -> lane-contiguous 16B fragments. grid (18432,2), block 256
__global__ void fold_kernel(const float* __restrict__ w0, const float* __restrict__ w1,
                            const float* __restrict__ s_arr, const float* __restrict__ d_arr,
                            unsigned short* __restrict__ wm0, unsigned short* __restrict__ wm1) {
    const int cv = blockIdx.y;
    const int e  = blockIdx.x * 256 + threadIdx.x;       // 0 .. 4718591
    const float* w = cv ? w1 : w0;
    unsigned short* wm = cv ? wm1 : wm0;
    const int slab = e >> 13;            // 0..575  = ((b*8)+cc)*9 + t
    const int idx  = e & 8191;
    const int b  = slab / 72;
    const int s2 = slab - b * 72;
    const int cc = s2 / 9;
    const int t  = s2 - cc * 9;
    const int o  = idx >> 5;
    const int c5 = idx & 31;
    const int c  = cc * 32 + c5;
    const float val = w[((size_t)o * 256 + c) * 9 + t] * 0.029462782549439483f  // sqrt(2/2304)
                    * s_arr[(cv * 8 + b) * 256 + c] * d_arr[(cv * 8 + b) * 256 + o];
    wm[((size_t)slab << 13) + (c5 >> 3) * 2048 + o * 8 + (c5 & 7)] = f2bf(val);
}

// x (fp32 NCHW) -> xq (bf16 NHWC8): [b][g=32][h][w][8ch]; grid 32768, block 256
__global__ void convert_kernel(const float* __restrict__ x, unsigned short* __restrict__ xq) {
    const int blk = blockIdx.x;
    const int hh  = blk & 127;
    const int bg_ = blk >> 7;
    const int g   = bg_ & 31;
    const int b   = bg_ >> 5;
    __shared__ float sx[8][128];
    const int tid = threadIdx.x;
#pragma unroll
    for (int i = 0; i < 4; ++i) {
        const int idx = tid + i * 256;
        const int c8 = idx >> 7, p = idx & 127;
        sx[c8][p] = x[(((size_t)b * 256 + g * 8 + c8) * 128 + hh) * 128 + p];
    }
    __syncthreads();
    if (tid < 128) {
        const int p = tid;
        unsigned short u[8];
#pragma unroll
        for (int j = 0; j < 8; ++j) u[j] = f2bf(sx[j][p]);
        *(int4*)(xq + ((((size_t)b * 32 + g) * 128 + hh) * 128 + p) * 8) = pack8(u);
    }
}

// ---------------------------------------------------------------------------
// Modulated conv, implicit GEMM: M=256 (o), N=256 (2 rows x 128 px), K=2304.
// 8 waves, wave tile 64o x 128px. Region schedule (3 taps/barrier), A region-
// double-buffered via global_load_lds. NO setprio in the loop (LLVM treats
// s_setprio as a scheduling fence -> blocks cross-tap ds_read/MFMA pipelining).
// B staged split ACROSS BARRIERS (fixes R11 race): rows{0,1}(cc+1) issue at
// top of cc's last region (their readers done at the r==1 barrier); rows{2,3}
// of the CURRENT cc issue at top of r==0 (r==0 reads only rows 0,1 -> disjoint;
// drained by r==0's region-end vmcnt(0) before r==1 reads row 2).
// All waits are vmcnt(0) lgkmcnt(0) (unconditionally safe).
// Fused: +bias, leaky*sqrt2, PixelNorm; !FINAL_OUT -> NHWC8 bf16, else fp32 NCHW.
template<bool FINAL_OUT>
__global__ __launch_bounds__(512, 2) void conv_kernel(
    const unsigned short* __restrict__ in_q, const unsigned short* __restrict__ wmod,
    const float* __restrict__ bias, const unsigned short* __restrict__ zpg,
    void* __restrict__ out_v) {

    // [0,98304)       A: 2 region-buffers x 3 slabs x 16KB
    // [98304,131072)  B: 4 rows x 4 koct x 128 px x 16B (single buffer)
    // [131072,131136) zero slot   [131136,132160) bias   [132160,136256) red
    __shared__ __align__(16) char lds[136256];

    const int tid  = threadIdx.x;
    const int b    = blockIdx.x & 7;          // XCD-affine (image b -> XCD b)
    const int rp   = blockIdx.x >> 3;         // 0..63 row pair
    const int h0   = rp * 2;
    const int lane = tid & 63;
    const int wr   = tid >> 6;                // 0..7
    const int wm   = wr & 3;                  // o-quarter (64 o's)
    const int wn   = wr >> 2;                 // row within pair
    const int l31  = lane & 31;
    const int khg  = lane >> 5;               // k-octet half

    float* sbias = (float*)(lds + 131136);
    if (tid < 256) sbias[tid] = bias[tid];
    if (tid < 4)   *(int4*)(lds + 131072 + tid * 16) = (int4){0, 0, 0, 0};

    // A frag byte offsets within a slab: [koct][o][16B]
    int aoff[2][2];
#pragma unroll
    for (int mb = 0; mb < 2; ++mb)
#pragma unroll
        for (int kh = 0; kh < 2; ++kh)
            aoff[mb][kh] = ((khg + 2 * kh) * 256 + wm * 64 + mb * 32 + l31) * 16;

    const unsigned short* wmb = wmod + (size_t)b * 589824;
    const unsigned short* xqb = in_q + (size_t)b * 4194304;   // [32][128][128][8]

    // stage 3 slabs (one region, 48KB) into region buffer nbuf
    auto issueA3 = [&](const char* src, int nbuf) {
        char* db = lds + nbuf * 49152 + wr * 2048;           // wave-uniform base
        const char* s = src + wr * 2048 + lane * 16;
#pragma unroll
        for (int j = 0; j < 3; ++j) {
            gld_lds16(s + j * 16384,        db + j * 16384);
            gld_lds16(s + j * 16384 + 1024, db + j * 16384 + 1024);
        }
    };

    // stage B rows [r0, r1) of channel-block cc
    auto issueBrows = [&](int cc, int r0, int r1) {
        const int koct = tid >> 7;            // wave-uniform (wr>>1)
        const int px   = tid & 127;
#pragma unroll
        for (int r = 0; r < 4; ++r) {
            if (r < r0 || r >= r1) continue;
            const int hin = h0 - 1 + r;
            const unsigned short* src = ((unsigned)hin < 128u)
                ? xqb + (((size_t)(cc * 4 + koct) * 128 + hin) * 128 + px) * 8
                : zpg;
            gld_lds16(src, lds + 98304 + r * 8192 + koct * 2048 + (wr & 1) * 1024);
        }
    };

    f32x16 acc[2][4];
#pragma unroll
    for (int mb = 0; mb < 2; ++mb)
#pragma unroll
        for (int nb = 0; nb < 4; ++nb)
#pragma unroll
            for (int r = 0; r < 16; ++r) acc[mb][nb][r] = 0.f;

    // prologue: region 0 A + all 4 B rows of cc0; full drain via __syncthreads
    issueA3((const char*)wmb, 0);
    issueBrows(0, 0, 4);
    __syncthreads();

    const char* gA = (const char*)wmb + 49152;   // region 1 onward
#pragma unroll 1
    for (int cc = 0; cc < 8; ++cc) {
#pragma unroll
        for (int r = 0; r < 3; ++r) {             // region = dy row = 3 taps
            const int g = cc * 3 + r;
            // top of r==0 (after the cc-boundary barrier): rows 2,3 of THIS cc
            // (r==0 reads only rows 0,1 -> disjoint; drained at r==0's end).
            if (r == 0 && cc > 0) issueBrows(cc, 2, 4);
            // top of cc's LAST region: rows 0,1 of cc+1 (readers done at the
            // r==1-end barrier; rows 0,1 not read again until next cc).
            if (r == 2 && cc < 7) issueBrows(cc + 1, 0, 2);
            if (g < 23) { issueA3(gA, (g + 1) & 1); gA += 49152; }
            const char* Ac = lds + (g & 1) * 49152;
#pragma unroll
            for (int i = 0; i < 3; ++i) {         // tap: dx = i
                short8 af[2][2], bf[4][2];
#pragma unroll
                for (int mb = 0; mb < 2; ++mb)
#pragma unroll
                    for (int kh = 0; kh < 2; ++kh)
                        af[mb][kh] = *(const short8*)(Ac + i * 16384 + aoff[mb][kh]);
#pragma unroll
                for (int nb = 0; nb < 4; ++nb)
#pragma unroll
                    for (int kh = 0; kh < 2; ++kh) {
                        int off = 98304 + (wn + r) * 8192 + (khg + 2 * kh) * 2048
                                + (nb * 32 + l31 + i - 1) * 16;
                        if (i == 0 && nb == 0) off = (l31 == 0)  ? 131072 : off;
                        if (i == 2 && nb == 3) off = (l31 == 31) ? 131072 : off;
                        bf[nb][kh] = *(const short8*)(lds + off);
                    }
#pragma unroll
                for (int kh = 0; kh < 2; ++kh)
#pragma unroll
                    for (int mb = 0; mb < 2; ++mb)
#pragma unroll
                        for (int nb = 0; nb < 4; ++nb)
                            acc[mb][nb] = __builtin_amdgcn_mfma_f32_32x32x16_bf16(
                                af[mb][kh], bf[nb][kh], acc[mb][nb], 0, 0, 0);
            }
            // region end: full drain (A(g+1) and any B rows have been in
            // flight under this region's 48 MFMAs -> mostly free).
            asm volatile("s_waitcnt vmcnt(0) lgkmcnt(0)" ::: "memory");
            __builtin_amdgcn_sched_barrier(0);
            __builtin_amdgcn_s_barrier();
        }
    }

    // ---------------- epilogue: bias + leaky*sqrt2 + PixelNorm ----------------
    float psum[4] = {0.f, 0.f, 0.f, 0.f};
    const float actGain = 1.4142135623730951f;
#pragma unroll
    for (int mb = 0; mb < 2; ++mb)
#pragma unroll
        for (int rg = 0; rg < 16; ++rg) {
            const int row = (rg & 3) + 8 * (rg >> 2) + 4 * khg;
            const float bo = sbias[wm * 64 + mb * 32 + row];
#pragma unroll
            for (int nb = 0; nb < 4; ++nb) {
                float v = acc[mb][nb][rg] + bo;
                v = (v > 0.f ? v : 0.2f * v) * actGain;
                acc[mb][nb][rg] = v;
                psum[nb] += v * v;
            }
        }
#pragma unroll
    for (int nb = 0; nb < 4; ++nb) psum[nb] += __shfl_xor(psum[nb], 32);
    float* red = (float*)(lds + 132160);      // [wn][wm][128 px]
    if (lane < 32) {
#pragma unroll
        for (int nb = 0; nb < 4; ++nb)
            red[(wn * 4 + wm) * 128 + nb * 32 + l31] = psum[nb];
    }
    __syncthreads();
    float rs[4];
#pragma unroll
    for (int nb = 0; nb < 4; ++nb) {
        const int p = nb * 32 + l31;
        const float ssum = red[(wn * 4 + 0) * 128 + p] + red[(wn * 4 + 1) * 128 + p]
                         + red[(wn * 4 + 2) * 128 + p] + red[(wn * 4 + 3) * 128 + p];
        rs[nb] = rsqrtf(ssum * (1.0f / 256.0f) + 1e-8f);
    }

    const int h = h0 + wn;
    if (FINAL_OUT) {
        float* outF = (float*)out_v;
#pragma unroll
        for (int mb = 0; mb < 2; ++mb)
#pragma unroll
            for (int rg = 0; rg < 16; ++rg) {
                const int row = (rg & 3) + 8 * (rg >> 2) + 4 * khg;
                const int o = wm * 64 + mb * 32 + row;
                const size_t rb = (((size_t)b * 256 + o) * 128 + h) * 128;
#pragma unroll
                for (int nb = 0; nb < 4; ++nb)
                    outF[rb + nb * 32 + l31] = acc[mb][nb][rg] * rs[nb];
            }
    } else {
        // per-wave transpose 32o x 128px -> NHWC8 bf16, fully unrolled (rule #20)
        unsigned short* outB = (unsigned short*)out_v;
        char* wreg = lds + wr * 8192;         // [128 px][32 o] bf16, chunk-swizzled
#pragma unroll
        for (int mb = 0; mb < 2; ++mb) {
#pragma unroll
            for (int rg = 0; rg < 16; rg += 2) {
                const int row = (rg & 3) + 8 * (rg >> 2) + 4 * khg;   // even, 0..31
#pragma unroll
                for (int nb = 0; nb < 4; ++nb) {
                    const int pxl = nb * 32 + l31;
                    const unsigned lo = f2bf(acc[mb][nb][rg]     * rs[nb]);
                    const unsigned hi = f2bf(acc[mb][nb][rg + 1] * rs[nb]);
                    *(unsigned int*)(wreg + pxl * 64 + (((row >> 3) ^ (pxl & 3)) << 4)
                                     + (row & 7) * 2) = lo | (hi << 16);
                }
            }
            asm volatile("s_waitcnt lgkmcnt(0)" ::: "memory");
#pragma unroll
            for (int oc = 0; oc < 4; ++oc)
#pragma unroll
                for (int ph = 0; ph < 2; ++ph) {
                    const int pxl = ph * 64 + lane;
                    const int4 v = *(const int4*)(wreg + pxl * 64 + ((oc ^ (pxl & 3)) << 4));
                    const int g = wm * 8 + mb * 4 + oc;
                    *(int4*)(outB + ((((size_t)b * 32 + g) * 128 + h) * 128 + pxl) * 8) = v;
                }
            asm volatile("s_waitcnt lgkmcnt(0)" ::: "memory");
        }
    }
}

// ---------------------------------------------------------------------------
extern "C" void kernel_launch(void* const* d_in, const int* in_sizes, int n_in,
                              void* d_out, int out_size, void* d_ws, size_t ws_size,
                              hipStream_t stream) {
    (void)in_sizes; (void)n_in; (void)out_size; (void)ws_size;
    const float* x      = (const float*)d_in[0];
    const float* latent = (const float*)d_in[1];
    const float* w0     = (const float*)d_in[2];
    const float* b0     = (const float*)d_in[3];
    const float* el0w   = (const float*)d_in[4];
    const float* el0b   = (const float*)d_in[5];
    const float* w1     = (const float*)d_in[6];
    const float* b1     = (const float*)d_in[7];
    const float* el1w   = (const float*)d_in[8];
    const float* el1b   = (const float*)d_in[9];

    char* ws = (char*)d_ws;
    float* s_arr = (float*)ws;                                   // 16 KB
    float* d_arr = (float*)(ws + 16384);                         // 16 KB
    float* wsq   = (float*)(ws + 32768);                         // 512 KB (reused as zero page)
    unsigned short* zpg = (unsigned short*)(ws + 32768);         // 256 B zeros (after demod)
    unsigned short* wm0 = (unsigned short*)(ws + 557056);        // 9.4 MB
    unsigned short* wm1 = (unsigned short*)(ws + 9994240);       // 9.4 MB
    unsigned short* xq  = (unsigned short*)(ws + 19431424);      // 67 MB
    unsigned short* tmp = (unsigned short*)(ws + 86540288);      // 67 MB

    style_kernel<<<16, 256, 0, stream>>>(latent, el0w, el0b, el1w, el1b, s_arr);
    wsq_kernel<<<512, 256, 0, stream>>>(w0, w1, wsq);
    demod_kernel<<<16, 256, 0, stream>>>(s_arr, wsq, d_arr);
    hipMemsetAsync(zpg, 0, 256, stream);   // wsq no longer needed; reuse as zero page
    fold_kernel<<<dim3(18432, 2), 256, 0, stream>>>(w0, w1, s_arr, d_arr, wm0, wm1);
    convert_kernel<<<32768, 256, 0, stream>>>(x, xq);

    conv_kernel<false><<<512, 512, 0, stream>>>(xq, wm0, b0, zpg, tmp);
    conv_kernel<true><<<512, 512, 0, stream>>>(tmp, wm1, b1, zpg, d_out);
}